// Round 14
// baseline (698.719 us; speedup 1.0000x reference)
//
#include <hip/hip_runtime.h>

// Problem dims
#define BB 32
#define TT 2048
#define FF 400
#define HH 1152
#define MM 65536      // BB*TT
#define NN 3456       // 3*HH
#define KK 800        // 2*FF
#define MT2 256       // MM/256  (BM=256)
#define NT 27         // NN/128  (BN=128)
#define KTL 25        // KK/32   (BK=32)
#define CH 64         // scan chunks
#define CL 32         // TT/CH

typedef __attribute__((ext_vector_type(8))) short short8;
typedef __attribute__((ext_vector_type(4))) float f32x4;
typedef __attribute__((ext_vector_type(16))) float f32x16;
typedef _Float16 hx4 __attribute__((ext_vector_type(4)));
typedef float f2 __attribute__((ext_vector_type(2)));

__device__ __forceinline__ unsigned short f2bf(float f) {
  union { float f; unsigned u; } v; v.f = f;
  unsigned r = v.u + 0x7FFFu + ((v.u >> 16) & 1u);
  return (unsigned short)(r >> 16);
}

// Gate layout (per sector, fp16):
// [mt(256)][ntS(9)][wave(wr*2+wc)][blk(mb*2+nb)][q(4)][lane(hi*32+l31)][4]
//   t = tm*256 + wr*128 + mb*32 + q*8 + hi*4 + rr   (m = b*2048 + t, mt = b*8+tm)
//   h = ntS*128 + wc*64 + nb*32 + l31
// One 8-B store per lane per (blk,q) -> 512 B contiguous per wave-store.
__device__ __forceinline__ size_t qOff(int mt, int ntS, int wr, int wc,
                                       int mb, int nb, int q, int hi, int l31) {
  return ((size_t)((mt * 9 + ntS) * 4 + wr * 2 + wc)) * 8192
         + (size_t)(((mb * 2 + nb) * 4 + q) * 256)
         + (size_t)((hi * 32 + l31) * 4);
}

// W [800][3456] fp32 -> bf16 tiled [nt][kt][kg(4)][n(128)][8]
__global__ __launch_bounds__(256) void pack_W_k(const float* __restrict__ W,
                                                unsigned short* __restrict__ Wws) {
  const int nt = blockIdx.x, kt = blockIdx.y;
  for (int c = threadIdx.x; c < 512; c += 256) {
    const int kg = c >> 7, n = c & 127;
    const int g = nt * 128 + n;
    const int k0 = kt * 32 + kg * 8;
    short8 o;
#pragma unroll
    for (int j = 0; j < 8; ++j) o[j] = (short)f2bf(W[(size_t)(k0 + j) * NN + g]);
    *(short8*)(Wws + ((size_t)(nt * KTL + kt) * 512 + c) * 8) = o;
  }
}

// merged = [x_t | x_{t-1}] -> bf16 tiled [mt][kt][kg(4)][mm(256)][8]
__global__ __launch_bounds__(256) void pack_A_k(const float* __restrict__ x,
                                                unsigned short* __restrict__ Aws) {
  const int mt = blockIdx.x, kt = blockIdx.y;
  for (int c = threadIdx.x; c < 1024; c += 256) {
    const int kg = c >> 8, mm = c & 255;
    const int m = mt * 256 + mm;
    const int b = m >> 11, t = m & 2047;
    const int k = kt * 32 + kg * 8;
    short8 o;
    const float* src = nullptr;
    if (k < FF) src = x + (size_t)(b * TT + t) * FF + k;
    else if (t > 0) src = x + (size_t)(b * TT + t - 1) * FF + (k - FF);
    if (src) {
      f32x4 v0 = *(const f32x4*)(src);
      f32x4 v1 = *(const f32x4*)(src + 4);
#pragma unroll
      for (int j = 0; j < 4; ++j) o[j] = (short)f2bf(v0[j]);
#pragma unroll
      for (int j = 0; j < 4; ++j) o[4 + j] = (short)f2bf(v1[j]);
    } else {
#pragma unroll
      for (int j = 0; j < 8; ++j) o[j] = 0;
    }
    *(short8*)(Aws + ((size_t)(mt * KTL + kt) * 1024 + c) * 8) = o;
  }
}

// C = A(bf16) * W(bf16), 256x128 tile, 4 INDEPENDENT waves (2M x 2N),
// per-wave 128x64 = 4x2 blocks of 32x32, mfma_f32_32x32x16_bf16 (half the
// instructions, 4096 FLOP/cyc vs 3378 for 16x16x32 — issue-port relief).
// No LDS, no barriers: fragments load directly global->regs (L2-resident
// after XCD supertile), double-buffered register sets.
__global__ __launch_bounds__(256, 2) void gemm_k(const unsigned short* __restrict__ Aws,
                                                 const unsigned short* __restrict__ Wws,
                                                 const float* __restrict__ bias,
                                                 _Float16* __restrict__ Zh,
                                                 _Float16* __restrict__ Fh,
                                                 _Float16* __restrict__ Oh) {
  // XCD supertile: 6912 = 8 XCDs x (3 ngroups x 32 mt x 9 nt)
  const int bid = blockIdx.x;
  const int xcd = bid & 7;
  const int local = bid >> 3;          // 0..863
  const int ng = local / 288;          // 0..2  (= gate sector)
  const int r0 = local - ng * 288;
  const int mtl = r0 / 9;
  const int nti = r0 - mtl * 9;
  const int mt = xcd * 32 + mtl;
  const int nt = ng * 9 + nti;

  const int tid = threadIdx.x;
  const int lane = tid & 63, w = tid >> 6;
  const int wr = w >> 1, wc = w & 1;          // 2 M-waves x 2 N-waves
  const int l31 = lane & 31, hi = lane >> 5;

  // 32x32x16 operand layout: A row = l31 (within 32-row block), k = hi*8 + j.
  // Packed [kg][mm][8] with kg = ks*2 + hi: per-lane base uses hi directly.
  const unsigned short* ga = Aws + (size_t)mt * KTL * 8192
                             + (size_t)hi * 2048 + (size_t)(wr * 128 + l31) * 8;
  const unsigned short* gb = Wws + (size_t)nt * KTL * 4096
                             + (size_t)hi * 1024 + (size_t)(wc * 64 + l31) * 8;

  f32x16 acc[4][2] = {};
  short8 a0[8], b0[4], a1[8], b1[4];   // [mb*2+ks], [nb*2+ks]

#define LOADT(AF, BF, tt)                                                     \
  do {                                                                        \
    const unsigned short* _a = ga + (size_t)(tt) * 8192;                      \
    const unsigned short* _b = gb + (size_t)(tt) * 4096;                      \
    _Pragma("unroll")                                                         \
    for (int mb = 0; mb < 4; ++mb)                                            \
      _Pragma("unroll")                                                       \
      for (int ks = 0; ks < 2; ++ks)                                          \
        AF[mb * 2 + ks] = *(const short8*)(_a + ks * 4096 + mb * 256);        \
    _Pragma("unroll")                                                         \
    for (int nb = 0; nb < 2; ++nb)                                            \
      _Pragma("unroll")                                                       \
      for (int ks = 0; ks < 2; ++ks)                                          \
        BF[nb * 2 + ks] = *(const short8*)(_b + ks * 2048 + nb * 256);        \
  } while (0)

#define MFMAC(AF, BF)                                                               \
  do {                                                                              \
    __builtin_amdgcn_s_setprio(1);                                                  \
    _Pragma("unroll")                                                               \
    for (int ks = 0; ks < 2; ++ks)                                                  \
      _Pragma("unroll")                                                             \
      for (int mb = 0; mb < 4; ++mb)                                                \
        _Pragma("unroll")                                                           \
        for (int nb = 0; nb < 2; ++nb)                                              \
          acc[mb][nb] = __builtin_amdgcn_mfma_f32_32x32x16_bf16(                    \
              AF[mb * 2 + ks], BF[nb * 2 + ks], acc[mb][nb], 0, 0, 0);              \
    __builtin_amdgcn_s_setprio(0);                                                  \
  } while (0)

  LOADT(a0, b0, 0);
  LOADT(a1, b1, 1);

#pragma unroll 1
  for (int t = 0; t < KTL - 1; t += 2) {
    MFMAC(a0, b0);                         // tile t (waits only set0's loads)
    if (t + 2 < KTL) LOADT(a0, b0, t + 2); // refill; ~2 MFMA clusters of hiding
    MFMAC(a1, b1);                         // tile t+1
    if (t + 3 < KTL) LOADT(a1, b1, t + 3);
  }
  MFMAC(a0, b0);  // final tile 24

#undef LOADT
#undef MFMAC

  // epilogue: bias + activation -> fp16 gates, 32x32 MFMA-native layout.
  // C/D: col = l31, row = (reg&3) + 8*(reg>>2) + 4*hi  (reg = q*4+rr)
  const int sector = ng;  // 0=z, 1=f, 2=o (supertile ngroups == sectors)
  const int ntS = nti;
  _Float16* __restrict__ dst = (sector == 0) ? Zh : ((sector == 1) ? Fh : Oh);
  const int hbase = nt * 128 + wc * 64 + l31;
  const size_t wavebase = ((size_t)((mt * 9 + ntS) * 4 + wr * 2 + wc)) * 8192
                          + (size_t)((hi * 32 + l31) * 4);
#pragma unroll
  for (int mb = 0; mb < 4; ++mb) {
#pragma unroll
    for (int nb = 0; nb < 2; ++nb) {
      const float bv = bias[hbase + nb * 32];
      f32x16 v = acc[mb][nb];
#pragma unroll
      for (int q = 0; q < 4; ++q) {
        hx4 hv;
#pragma unroll
        for (int rr = 0; rr < 4; ++rr) {
          float xv = v[q * 4 + rr] + bv;
          float s;
          if (sector == 0) {
            float e = __expf(2.0f * xv);   // tanh(x) = 1 - 2/(e^{2x}+1)
            s = 1.0f - 2.0f / (e + 1.0f);
          } else {
            s = 1.0f / (1.0f + __expf(-xv));
          }
          hv[rr] = (_Float16)s;
        }
        __builtin_nontemporal_store(hv,
            (hx4*)(dst + wavebase + (size_t)(((mb * 2 + nb) * 4 + q) * 256)));
      }
    }
  }
}

// ---- chunked parallel scan of h_t = (1-f)h + f z, CH=64 chunks of CL=32 ----
// chunk ch = tm*8 + wr*4 + mb; within-chunk t5 = q*8 + hi*4 + rr (ascending).
// grid 9216 = b(32) x hb(9) x chunk-pair(32); 256 thr = hloc(128) x sub(2).
__global__ __launch_bounds__(256) void scan1_k(const _Float16* __restrict__ Zh,
                                               const _Float16* __restrict__ Fh,
                                               f2* __restrict__ PQ) {
  const int bid = blockIdx.x;
  const int b = bid / 288;
  const int rem = bid - b * 288;
  const int hb = rem >> 5, cp = rem & 31;
  const int tid = threadIdx.x;
  const int hloc = tid & 127, sub = tid >> 7;
  const int ch = cp * 2 + sub;
  const int wc = hloc >> 6, nb = (hloc >> 5) & 1, l31 = hloc & 31;
  const int tm = ch >> 3, wr = (ch >> 2) & 1, mb = ch & 3;
  const int mt = b * 8 + tm;

  float P = 1.f, Q = 0.f;
#pragma unroll
  for (int q = 0; q < 4; ++q) {
#pragma unroll
    for (int hi = 0; hi < 2; ++hi) {
      const size_t off = qOff(mt, hb, wr, wc, mb, nb, q, hi, l31);
      hx4 z = __builtin_nontemporal_load((const hx4*)(Zh + off));
      hx4 f = __builtin_nontemporal_load((const hx4*)(Fh + off));
#pragma unroll
      for (int s = 0; s < 4; ++s) {
        float fv = (float)f[s], a = 1.f - fv;
        P *= a;
        Q = a * Q + fv * (float)z[s];
      }
    }
  }
  f2 o; o[0] = P; o[1] = Q;
  PQ[((size_t)b * CH + ch) * HH + hb * 128 + hloc] = o;
}

// pass 2: sequential over 64 chunks per (b,h): start states
__global__ __launch_bounds__(256) void scan2_k(const f2* __restrict__ PQ,
                                               const float* __restrict__ h0,
                                               float* __restrict__ Hs) {
  const int idx = blockIdx.x * 256 + threadIdx.x;   // [b][h]
  const int b = idx / HH, h = idx - b * HH;
  float cur = h0[b * HH + h];
#pragma unroll 4
  for (int c = 0; c < CH; ++c) {
    Hs[((size_t)b * CH + c) * HH + h] = cur;
    f2 pq = PQ[((size_t)b * CH + c) * HH + h];
    cur = pq[0] * cur + pq[1];
  }
}

// pass 3: recompute within chunk (exact sequential fmaf), c = o*h.
// LDS transpose (64 t-rows x 128 h, stride 132); write phase lane-contiguous.
__global__ __launch_bounds__(256) void scan3_k(const _Float16* __restrict__ Zh,
                                               const _Float16* __restrict__ Fh,
                                               const _Float16* __restrict__ Oh,
                                               const float* __restrict__ Hs,
                                               float* __restrict__ Out) {
  __shared__ float buf[64 * 132];
  const int bid = blockIdx.x;
  const int b = bid / 288;
  const int rem = bid - b * 288;
  const int hb = rem >> 5, cp = rem & 31;
  const int tid = threadIdx.x;
  const int hloc = tid & 127, sub = tid >> 7;
  const int ch = cp * 2 + sub;
  const int h = hb * 128 + hloc;
  const int wc = hloc >> 6, nb = (hloc >> 5) & 1, l31 = hloc & 31;
  const int tm = ch >> 3, wr = (ch >> 2) & 1, mb = ch & 3;
  const int mt = b * 8 + tm;

  float hcur = Hs[((size_t)b * CH + ch) * HH + h];
#pragma unroll
  for (int q = 0; q < 4; ++q) {
#pragma unroll
    for (int hi = 0; hi < 2; ++hi) {
      const size_t off = qOff(mt, hb, wr, wc, mb, nb, q, hi, l31);
      hx4 z = __builtin_nontemporal_load((const hx4*)(Zh + off));
      hx4 f = __builtin_nontemporal_load((const hx4*)(Fh + off));
      hx4 o = __builtin_nontemporal_load((const hx4*)(Oh + off));
#pragma unroll
      for (int s = 0; s < 4; ++s) {
        hcur = fmaf((float)f[s], (float)z[s] - hcur, hcur);
        buf[(sub * 32 + q * 8 + hi * 4 + s) * 132 + hloc] = (float)o[s] * hcur;
      }
    }
  }
  __syncthreads();
  // write phase: 32-lane group g (=tid>>5) owns rows g*8..g*8+7; lane32 covers
  // the row's 128 floats in 16-B chunks -> 512 B contiguous per instruction.
  const int lane32 = tid & 31, grp = tid >> 5;
  float* outb = Out + (size_t)(b * TT + cp * 64) * HH + hb * 128 + lane32 * 4;
#pragma unroll
  for (int rr = 0; rr < 8; ++rr) {
    const int row = grp * 8 + rr;
    f32x4 v = *(const f32x4*)&buf[row * 132 + lane32 * 4];
    __builtin_nontemporal_store(v, (f32x4*)(outb + (size_t)row * HH));
  }
}

extern "C" void kernel_launch(void* const* d_in, const int* in_sizes, int n_in,
                              void* d_out, int out_size, void* d_ws, size_t ws_size,
                              hipStream_t stream) {
  const float* x    = (const float*)d_in[0];
  const float* W    = (const float*)d_in[1];
  const float* bias = (const float*)d_in[2];
  const float* h0   = (const float*)d_in[3];
  float* Out = (float*)d_out;
  char* ws = (char*)d_ws;

  // ws layout
  const size_t A_BYTES  = (size_t)MT2 * KTL * 16384;       // 104,857,600
  const size_t W_BYTES  = (size_t)NT * KTL * 8192;         //   5,529,600
  const size_t G_BYTES  = (size_t)MM * HH * 2;             // 150,994,944 per gate (fp16)
  const size_t PQ_BYTES = (size_t)BB * CH * HH * 8;        //  18,874,368
  unsigned short* Aws = (unsigned short*)ws;
  unsigned short* Wws = (unsigned short*)(ws + A_BYTES);
  _Float16* Zh = (_Float16*)(ws + A_BYTES + W_BYTES);
  _Float16* Fh = (_Float16*)(ws + A_BYTES + W_BYTES + G_BYTES);
  _Float16* Oh = (_Float16*)(ws + A_BYTES + W_BYTES + 2 * G_BYTES);
  f2* PQ = (f2*)(ws + A_BYTES + W_BYTES + 3 * G_BYTES);
  float* Hs = (float*)(ws + A_BYTES + W_BYTES + 3 * G_BYTES + PQ_BYTES);
  (void)ws_size; (void)in_sizes; (void)n_in; (void)out_size;

  pack_W_k<<<dim3(NT, KTL), 256, 0, stream>>>(W, Wws);
  pack_A_k<<<dim3(MT2, KTL), 256, 0, stream>>>(x, Aws);
  gemm_k<<<MT2 * NT, 256, 0, stream>>>(Aws, Wws, bias, Zh, Fh, Oh);
  scan1_k<<<BB * 9 * 32, 256, 0, stream>>>(Zh, Fh, PQ);
  scan2_k<<<BB * HH / 256, 256, 0, stream>>>(PQ, h0, Hs);
  scan3_k<<<BB * 9 * 32, 256, 0, stream>>>(Zh, Fh, Oh, Hs, Out);
}

// Round 15
// 636.255 us; speedup vs baseline: 1.0982x; 1.0982x over previous
//
#include <hip/hip_runtime.h>

// Problem dims
#define BB 32
#define TT 2048
#define FF 400
#define HH 1152
#define MM 65536      // BB*TT
#define NN 3456       // 3*HH
#define KK 800        // 2*FF
#define MT2 256       // MM/256  (BM=256)
#define NT 27         // NN/128  (BN=128)
#define KTL 25        // KK/32   (BK=32)
#define CH 64         // scan chunks
#define CL 32         // TT/CH

typedef __attribute__((ext_vector_type(8))) short short8;
typedef __attribute__((ext_vector_type(4))) float f32x4;
typedef _Float16 hx4 __attribute__((ext_vector_type(4)));
typedef float f2 __attribute__((ext_vector_type(2)));

__device__ __forceinline__ unsigned short f2bf(float f) {
  union { float f; unsigned u; } v; v.f = f;
  unsigned r = v.u + 0x7FFFu + ((v.u >> 16) & 1u);
  return (unsigned short)(r >> 16);
}

// Gate layout (per sector, fp16): [mt(256)][ntS(9)][wr(2)][wc(2)][mr(8)][nr(4)][kg(4)][l15(16)][r(4)]
//   m = mt*256 + wr*128 + mr*16 + kg*4 + r    (m = b*2048 + t)
//   h = ntS*128 + wc*64 + nr*16 + l15
__device__ __forceinline__ size_t quadOff(int mt, int ntS, int wr, int wc,
                                          int mr, int nr, int kg, int l15) {
  return ((((size_t)(mt * 9 + ntS) * 2 + wr) * 2 + wc) * 32 + mr * 4 + nr) * 256
         + (size_t)(kg * 16 + l15) * 4;
}

// W [800][3456] fp32 -> bf16 tiled [nt][kt][kg(4)][n(128)][8]
__global__ __launch_bounds__(256) void pack_W_k(const float* __restrict__ W,
                                                unsigned short* __restrict__ Wws) {
  const int nt = blockIdx.x, kt = blockIdx.y;
  for (int c = threadIdx.x; c < 512; c += 256) {
    const int kg = c >> 7, n = c & 127;
    const int g = nt * 128 + n;
    const int k0 = kt * 32 + kg * 8;
    short8 o;
#pragma unroll
    for (int j = 0; j < 8; ++j) o[j] = (short)f2bf(W[(size_t)(k0 + j) * NN + g]);
    *(short8*)(Wws + ((size_t)(nt * KTL + kt) * 512 + c) * 8) = o;
  }
}

// merged = [x_t | x_{t-1}] -> bf16 tiled [mt][kt][kg(4)][mm(256)][8]
__global__ __launch_bounds__(256) void pack_A_k(const float* __restrict__ x,
                                                unsigned short* __restrict__ Aws) {
  const int mt = blockIdx.x, kt = blockIdx.y;
  for (int c = threadIdx.x; c < 1024; c += 256) {
    const int kg = c >> 8, mm = c & 255;
    const int m = mt * 256 + mm;
    const int b = m >> 11, t = m & 2047;
    const int k = kt * 32 + kg * 8;
    short8 o;
    const float* src = nullptr;
    if (k < FF) src = x + (size_t)(b * TT + t) * FF + k;
    else if (t > 0) src = x + (size_t)(b * TT + t - 1) * FF + (k - FF);
    if (src) {
      f32x4 v0 = *(const f32x4*)(src);
      f32x4 v1 = *(const f32x4*)(src + 4);
#pragma unroll
      for (int j = 0; j < 4; ++j) o[j] = (short)f2bf(v0[j]);
#pragma unroll
      for (int j = 0; j < 4; ++j) o[4 + j] = (short)f2bf(v1[j]);
    } else {
#pragma unroll
      for (int j = 0; j < 8; ++j) o[j] = 0;
    }
    *(short8*)(Aws + ((size_t)(mt * KTL + kt) * 1024 + c) * 8) = o;
  }
}

// C = A(bf16) * W(bf16), 256x128 tile, 4 INDEPENDENT waves (2M x 2N),
// per-wave 128x64, BK=32, mfma_f32_16x16x32_bf16 (R13 proven core).
// No LDS, no barriers: fragments load directly global->regs (L2-resident
// after XCD supertile), double-buffered register sets.
// NEW: per-wave cyclic K-order (tile (s + 6*w) % 25) — de-phases the two
// co-resident waves per SIMD so their L2-load stall windows interleave with
// each other's MFMA windows instead of colliding (R13's MfmaUtil was exactly
// 1-wave's 155/352 cyc — simultaneous stalls).
__global__ __launch_bounds__(256, 2) void gemm_k(const unsigned short* __restrict__ Aws,
                                                 const unsigned short* __restrict__ Wws,
                                                 const float* __restrict__ bias,
                                                 _Float16* __restrict__ Zh,
                                                 _Float16* __restrict__ Fh,
                                                 _Float16* __restrict__ Oh) {
  // XCD supertile: 6912 = 8 XCDs x (3 ngroups x 32 mt x 9 nt)
  const int bid = blockIdx.x;
  const int xcd = bid & 7;
  const int local = bid >> 3;          // 0..863
  const int ng = local / 288;          // 0..2  (= gate sector)
  const int r0 = local - ng * 288;
  const int mtl = r0 / 9;
  const int nti = r0 - mtl * 9;
  const int mt = xcd * 32 + mtl;
  const int nt = ng * 9 + nti;

  const int tid = threadIdx.x;
  const int lane = tid & 63, w = tid >> 6;
  const int wr = w >> 1, wc = w & 1;          // 2 M-waves x 2 N-waves
  const int l15 = lane & 15, kg = lane >> 4;

  // per-lane fragment base addresses (16-lane groups read 256B contiguous)
  const unsigned short* ga = Aws + (size_t)mt * KTL * 8192
                             + (size_t)(kg * 256 + wr * 128 + l15) * 8;
  const unsigned short* gb = Wws + (size_t)nt * KTL * 4096
                             + (size_t)(kg * 128 + wc * 64 + l15) * 8;

  // per-wave K-order offset: waves start 6 tiles apart (accumulation is
  // order-independent; no cross-wave sharing exists in this kernel).
  const int koff = w * 6;
#define TIDX(s) ({ int _u = (s) + koff; _u >= KTL ? _u - KTL : _u; })

  f32x4 acc[8][4] = {};
  short8 a0[8], b0[4], a1[8], b1[4];

#define LOADT(AF, BF, tt)                                                    \
  do {                                                                       \
    const unsigned short* _a = ga + (size_t)(tt) * 8192;                     \
    const unsigned short* _b = gb + (size_t)(tt) * 4096;                     \
    _Pragma("unroll")                                                        \
    for (int mr = 0; mr < 8; ++mr) AF[mr] = *(const short8*)(_a + mr * 128); \
    _Pragma("unroll")                                                        \
    for (int nr = 0; nr < 4; ++nr) BF[nr] = *(const short8*)(_b + nr * 128); \
  } while (0)

#define MFMAC(AF, BF)                                                              \
  do {                                                                             \
    __builtin_amdgcn_s_setprio(1);                                                 \
    _Pragma("unroll")                                                              \
    for (int mr = 0; mr < 8; ++mr)                                                 \
      _Pragma("unroll")                                                            \
      for (int nr = 0; nr < 4; ++nr)                                               \
        acc[mr][nr] = __builtin_amdgcn_mfma_f32_16x16x32_bf16(AF[mr], BF[nr],      \
                                                              acc[mr][nr], 0, 0, 0); \
    __builtin_amdgcn_s_setprio(0);                                                 \
  } while (0)

  LOADT(a0, b0, TIDX(0));
  LOADT(a1, b1, TIDX(1));

#pragma unroll 1
  for (int t = 0; t < KTL - 1; t += 2) {
    MFMAC(a0, b0);                                // tile seq t
    if (t + 2 < KTL) LOADT(a0, b0, TIDX(t + 2));  // refill set0
    MFMAC(a1, b1);                                // tile seq t+1
    if (t + 3 < KTL) LOADT(a1, b1, TIDX(t + 3));
  }
  MFMAC(a0, b0);  // final (seq 24)

#undef LOADT
#undef MFMAC
#undef TIDX

  // epilogue: bias + activation -> fp16 gates, MFMA-native layout.
  const int sector = ng;  // 0=z, 1=f, 2=o (supertile ngroups == sectors)
  const int ntS = nti;
  _Float16* __restrict__ dst = (sector == 0) ? Zh : ((sector == 1) ? Fh : Oh);
  const int gbase = nt * 128 + wc * 64 + l15;
  const size_t wavebase = (((size_t)(mt * 9 + ntS) * 2 + wr) * 2 + wc) * 8192 + (size_t)lane * 4;
#pragma unroll
  for (int nr = 0; nr < 4; ++nr) {
    const float bv = bias[gbase + nr * 16];
#pragma unroll
    for (int mr = 0; mr < 8; ++mr) {
      f32x4 v = acc[mr][nr];
      hx4 hv;
#pragma unroll
      for (int rr = 0; rr < 4; ++rr) {
        float xv = v[rr] + bv;
        float s;
        if (sector == 0) {
          float e = __expf(2.0f * xv);   // tanh(x) = 1 - 2/(e^{2x}+1)
          s = 1.0f - 2.0f / (e + 1.0f);
        } else {
          s = 1.0f / (1.0f + __expf(-xv));
        }
        hv[rr] = (_Float16)s;
      }
      __builtin_nontemporal_store(hv, (hx4*)(dst + wavebase + (size_t)(mr * 4 + nr) * 256));
    }
  }
}

// ---- chunked parallel scan of h_t = (1-f)h + f z, CH=64 chunks of CL=32 ----
// t bits: [10:8]=tm [7]=wr [6:4]=mr [3:2]=kg [1:0]=r; chunk ch = t>>5 = tm*8+wr*4+(mr>>1).
// grid 9216 = b(32) x hb(9) x chunk-pair(32); 256 thr = hloc(128) x sub(2).
__global__ __launch_bounds__(256) void scan1_k(const _Float16* __restrict__ Zh,
                                               const _Float16* __restrict__ Fh,
                                               f2* __restrict__ PQ) {
  const int bid = blockIdx.x;
  const int b = bid / 288;
  const int rem = bid - b * 288;
  const int hb = rem >> 5, cp = rem & 31;
  const int tid = threadIdx.x;
  const int hloc = tid & 127, sub = tid >> 7;
  const int ch = cp * 2 + sub;
  const int ntS = hb, wc = hloc >> 6, nr = (hloc >> 4) & 3, l15 = hloc & 15;
  const int tm = ch >> 3, wr = (ch >> 2) & 1, mrh = ch & 3;
  const int mt = b * 8 + tm;

  float P = 1.f, Q = 0.f;
#pragma unroll
  for (int mi = 0; mi < 2; ++mi) {
#pragma unroll
    for (int kg = 0; kg < 4; ++kg) {
      const size_t off = quadOff(mt, ntS, wr, wc, mrh * 2 + mi, nr, kg, l15);
      hx4 z = __builtin_nontemporal_load((const hx4*)(Zh + off));
      hx4 f = __builtin_nontemporal_load((const hx4*)(Fh + off));
#pragma unroll
      for (int s = 0; s < 4; ++s) {
        float fv = (float)f[s], a = 1.f - fv;
        P *= a;
        Q = a * Q + fv * (float)z[s];
      }
    }
  }
  f2 o; o[0] = P; o[1] = Q;
  PQ[((size_t)b * CH + ch) * HH + hb * 128 + hloc] = o;
}

// pass 2: sequential over 64 chunks per (b,h): start states
__global__ __launch_bounds__(256) void scan2_k(const f2* __restrict__ PQ,
                                               const float* __restrict__ h0,
                                               float* __restrict__ Hs) {
  const int idx = blockIdx.x * 256 + threadIdx.x;   // [b][h]
  const int b = idx / HH, h = idx - b * HH;
  float cur = h0[b * HH + h];
#pragma unroll 4
  for (int c = 0; c < CH; ++c) {
    Hs[((size_t)b * CH + c) * HH + h] = cur;
    f2 pq = PQ[((size_t)b * CH + c) * HH + h];
    cur = pq[0] * cur + pq[1];
  }
}

// pass 3: recompute within chunk (exact sequential fmaf), c = o*h.
// LDS transpose (64 t-rows x 128 h, stride 132); write phase lane-contiguous.
__global__ __launch_bounds__(256) void scan3_k(const _Float16* __restrict__ Zh,
                                               const _Float16* __restrict__ Fh,
                                               const _Float16* __restrict__ Oh,
                                               const float* __restrict__ Hs,
                                               float* __restrict__ Out) {
  __shared__ float buf[64 * 132];
  const int bid = blockIdx.x;
  const int b = bid / 288;
  const int rem = bid - b * 288;
  const int hb = rem >> 5, cp = rem & 31;
  const int tid = threadIdx.x;
  const int hloc = tid & 127, sub = tid >> 7;
  const int ch = cp * 2 + sub;
  const int h = hb * 128 + hloc;
  const int ntS = hb, wc = hloc >> 6, nr = (hloc >> 4) & 3, l15 = hloc & 15;
  const int tm = ch >> 3, wr = (ch >> 2) & 1, mrh = ch & 3;
  const int mt = b * 8 + tm;

  float hcur = Hs[((size_t)b * CH + ch) * HH + h];
#pragma unroll
  for (int mi = 0; mi < 2; ++mi) {
#pragma unroll
    for (int kg = 0; kg < 4; ++kg) {
      const size_t off = quadOff(mt, ntS, wr, wc, mrh * 2 + mi, nr, kg, l15);
      hx4 z = __builtin_nontemporal_load((const hx4*)(Zh + off));
      hx4 f = __builtin_nontemporal_load((const hx4*)(Fh + off));
      hx4 o = __builtin_nontemporal_load((const hx4*)(Oh + off));
#pragma unroll
      for (int s = 0; s < 4; ++s) {
        hcur = fmaf((float)f[s], (float)z[s] - hcur, hcur);
        buf[(sub * 32 + mi * 16 + kg * 4 + s) * 132 + hloc] = (float)o[s] * hcur;
      }
    }
  }
  __syncthreads();
  // write phase: 32-lane group g (=tid>>5) owns rows g*8..g*8+7; lane32 covers
  // the row's 128 floats in 16-B chunks -> 512 B contiguous per instruction.
  const int lane32 = tid & 31, grp = tid >> 5;
  float* outb = Out + (size_t)(b * TT + cp * 64) * HH + hb * 128 + lane32 * 4;
#pragma unroll
  for (int rr = 0; rr < 8; ++rr) {
    const int row = grp * 8 + rr;
    f32x4 v = *(const f32x4*)&buf[row * 132 + lane32 * 4];
    __builtin_nontemporal_store(v, (f32x4*)(outb + (size_t)row * HH));
  }
}

extern "C" void kernel_launch(void* const* d_in, const int* in_sizes, int n_in,
                              void* d_out, int out_size, void* d_ws, size_t ws_size,
                              hipStream_t stream) {
  const float* x    = (const float*)d_in[0];
  const float* W    = (const float*)d_in[1];
  const float* bias = (const float*)d_in[2];
  const float* h0   = (const float*)d_in[3];
  float* Out = (float*)d_out;
  char* ws = (char*)d_ws;

  // ws layout
  const size_t A_BYTES  = (size_t)MT2 * KTL * 16384;       // 104,857,600
  const size_t W_BYTES  = (size_t)NT * KTL * 8192;         //   5,529,600
  const size_t G_BYTES  = (size_t)MM * HH * 2;             // 150,994,944 per gate (fp16)
  const size_t PQ_BYTES = (size_t)BB * CH * HH * 8;        //  18,874,368
  unsigned short* Aws = (unsigned short*)ws;
  unsigned short* Wws = (unsigned short*)(ws + A_BYTES);
  _Float16* Zh = (_Float16*)(ws + A_BYTES + W_BYTES);
  _Float16* Fh = (_Float16*)(ws + A_BYTES + W_BYTES + G_BYTES);
  _Float16* Oh = (_Float16*)(ws + A_BYTES + W_BYTES + 2 * G_BYTES);
  f2* PQ = (f2*)(ws + A_BYTES + W_BYTES + 3 * G_BYTES);
  float* Hs = (float*)(ws + A_BYTES + W_BYTES + 3 * G_BYTES + PQ_BYTES);
  (void)ws_size; (void)in_sizes; (void)n_in; (void)out_size;

  pack_W_k<<<dim3(NT, KTL), 256, 0, stream>>>(W, Wws);
  pack_A_k<<<dim3(MT2, KTL), 256, 0, stream>>>(x, Aws);
  gemm_k<<<MT2 * NT, 256, 0, stream>>>(Aws, Wws, bias, Zh, Fh, Oh);
  scan1_k<<<BB * 9 * 32, 256, 0, stream>>>(Zh, Fh, PQ);
  scan2_k<<<BB * HH / 256, 256, 0, stream>>>(PQ, h0, Hs);
  scan3_k<<<BB * 9 * 32, 256, 0, stream>>>(Zh, Fh, Oh, Hs, Out);
}

// Round 16
// 614.789 us; speedup vs baseline: 1.1365x; 1.0349x over previous
//
#include <hip/hip_runtime.h>

// Problem dims
#define BB 32
#define TT 2048
#define FF 400
#define HH 1152
#define MM 65536      // BB*TT
#define NN 3456       // 3*HH
#define KK 800        // 2*FF
#define MT2 256       // MM/256  (BM=256)
#define NT 27         // NN/128  (BN=128)
#define KTL 25        // KK/32   (BK=32)
#define CH 64         // scan chunks
#define CL 32         // TT/CH

typedef __attribute__((ext_vector_type(8))) short short8;
typedef __attribute__((ext_vector_type(4))) float f32x4;
typedef _Float16 hx4 __attribute__((ext_vector_type(4)));
typedef _Float16 hx8 __attribute__((ext_vector_type(8)));
typedef float f2 __attribute__((ext_vector_type(2)));

__device__ __forceinline__ unsigned short f2bf(float f) {
  union { float f; unsigned u; } v; v.f = f;
  unsigned r = v.u + 0x7FFFu + ((v.u >> 16) & 1u);
  return (unsigned short)(r >> 16);
}

// Gate layout (per sector, fp16), 16-B units pairing mr-halves:
// [mt(256)][ntS(9)][wr(2)][wc(2)][segP = mrh(4)*4+nr(4)][lane(64)][8]
//   where the 8 = { half=0: r 0..3 , half=1: r 0..3 }, mr = 2*mrh + half
//   t = wr*128 + mrh*32 + half*16 + kg*4 + r   (lane = kg*16+l15; m = mt*256+t)
//   h = ntS*128 + wc*64 + nr*16 + l15
// Epilogue: one 16-B store per lane per segP -> 1 KB contiguous per wave-inst.
__device__ __forceinline__ size_t unitOff(int mt, int ntS, int wr, int wc,
                                          int mrh, int nr, int kg, int l15) {
  return (((size_t)(mt * 9 + ntS) * 2 + wr) * 2 + wc) * 8192
         + (size_t)(mrh * 4 + nr) * 512 + (size_t)(kg * 16 + l15) * 8;
}

// W [800][3456] fp32 -> bf16 tiled [nt][kt][kg(4)][n(128)][8]
__global__ __launch_bounds__(256) void pack_W_k(const float* __restrict__ W,
                                                unsigned short* __restrict__ Wws) {
  const int nt = blockIdx.x, kt = blockIdx.y;
  for (int c = threadIdx.x; c < 512; c += 256) {
    const int kg = c >> 7, n = c & 127;
    const int g = nt * 128 + n;
    const int k0 = kt * 32 + kg * 8;
    short8 o;
#pragma unroll
    for (int j = 0; j < 8; ++j) o[j] = (short)f2bf(W[(size_t)(k0 + j) * NN + g]);
    *(short8*)(Wws + ((size_t)(nt * KTL + kt) * 512 + c) * 8) = o;
  }
}

// merged = [x_t | x_{t-1}] -> bf16 tiled [mt][kt][kg(4)][mm(256)][8]
__global__ __launch_bounds__(256) void pack_A_k(const float* __restrict__ x,
                                                unsigned short* __restrict__ Aws) {
  const int mt = blockIdx.x, kt = blockIdx.y;
  for (int c = threadIdx.x; c < 1024; c += 256) {
    const int kg = c >> 8, mm = c & 255;
    const int m = mt * 256 + mm;
    const int b = m >> 11, t = m & 2047;
    const int k = kt * 32 + kg * 8;
    short8 o;
    const float* src = nullptr;
    if (k < FF) src = x + (size_t)(b * TT + t) * FF + k;
    else if (t > 0) src = x + (size_t)(b * TT + t - 1) * FF + (k - FF);
    if (src) {
      f32x4 v0 = *(const f32x4*)(src);
      f32x4 v1 = *(const f32x4*)(src + 4);
#pragma unroll
      for (int j = 0; j < 4; ++j) o[j] = (short)f2bf(v0[j]);
#pragma unroll
      for (int j = 0; j < 4; ++j) o[4 + j] = (short)f2bf(v1[j]);
    } else {
#pragma unroll
      for (int j = 0; j < 8; ++j) o[j] = 0;
    }
    *(short8*)(Aws + ((size_t)(mt * KTL + kt) * 1024 + c) * 8) = o;
  }
}

// C = A(bf16) * W(bf16), 256x128 tile, 4 INDEPENDENT waves (2M x 2N),
// per-wave 128x64, BK=32, mfma_f32_16x16x32_bf16 (R13 proven core, in-order K).
// No LDS, no barriers: fragments load directly global->regs (L1/L2-resident
// after XCD supertile; both blocks/CU share the A tile in L1), double-buffered
// register sets. Load-path bound at ~352 cyc/tile (measured R13).
__global__ __launch_bounds__(256, 2) void gemm_k(const unsigned short* __restrict__ Aws,
                                                 const unsigned short* __restrict__ Wws,
                                                 const float* __restrict__ bias,
                                                 _Float16* __restrict__ Zh,
                                                 _Float16* __restrict__ Fh,
                                                 _Float16* __restrict__ Oh) {
  // XCD supertile: 6912 = 8 XCDs x (3 ngroups x 32 mt x 9 nt)
  const int bid = blockIdx.x;
  const int xcd = bid & 7;
  const int local = bid >> 3;          // 0..863
  const int ng = local / 288;          // 0..2  (= gate sector)
  const int r0 = local - ng * 288;
  const int mtl = r0 / 9;
  const int nti = r0 - mtl * 9;
  const int mt = xcd * 32 + mtl;
  const int nt = ng * 9 + nti;

  const int tid = threadIdx.x;
  const int lane = tid & 63, w = tid >> 6;
  const int wr = w >> 1, wc = w & 1;          // 2 M-waves x 2 N-waves
  const int l15 = lane & 15, kg = lane >> 4;

  // per-lane fragment base addresses (16-lane groups read 256B contiguous)
  const unsigned short* ga = Aws + (size_t)mt * KTL * 8192
                             + (size_t)(kg * 256 + wr * 128 + l15) * 8;
  const unsigned short* gb = Wws + (size_t)nt * KTL * 4096
                             + (size_t)(kg * 128 + wc * 64 + l15) * 8;

  f32x4 acc[8][4] = {};
  short8 a0[8], b0[4], a1[8], b1[4];

#define LOADT(AF, BF, tt)                                                    \
  do {                                                                       \
    const unsigned short* _a = ga + (size_t)(tt) * 8192;                     \
    const unsigned short* _b = gb + (size_t)(tt) * 4096;                     \
    _Pragma("unroll")                                                        \
    for (int mr = 0; mr < 8; ++mr) AF[mr] = *(const short8*)(_a + mr * 128); \
    _Pragma("unroll")                                                        \
    for (int nr = 0; nr < 4; ++nr) BF[nr] = *(const short8*)(_b + nr * 128); \
  } while (0)

#define MFMAC(AF, BF)                                                              \
  do {                                                                             \
    __builtin_amdgcn_s_setprio(1);                                                 \
    _Pragma("unroll")                                                              \
    for (int mr = 0; mr < 8; ++mr)                                                 \
      _Pragma("unroll")                                                            \
      for (int nr = 0; nr < 4; ++nr)                                               \
        acc[mr][nr] = __builtin_amdgcn_mfma_f32_16x16x32_bf16(AF[mr], BF[nr],      \
                                                              acc[mr][nr], 0, 0, 0); \
    __builtin_amdgcn_s_setprio(0);                                                 \
  } while (0)

  LOADT(a0, b0, 0);
  LOADT(a1, b1, 1);

#pragma unroll 1
  for (int t = 0; t < KTL - 1; t += 2) {
    MFMAC(a0, b0);                         // tile t (waits only set0's loads)
    if (t + 2 < KTL) LOADT(a0, b0, t + 2); // refill; ~2 MFMA clusters of hiding
    MFMAC(a1, b1);                         // tile t+1
    if (t + 3 < KTL) LOADT(a1, b1, t + 3);
  }
  MFMAC(a0, b0);  // final tile 24

#undef LOADT
#undef MFMAC

  // epilogue: bias + activation -> fp16 gates, paired-quad layout
  // (one hx8 = 16-B store per lane per (mrh,nr) -> 1 KB/wave-inst).
  const int sector = ng;  // 0=z, 1=f, 2=o (supertile ngroups == sectors)
  const int ntS = nti;
  _Float16* __restrict__ dst = (sector == 0) ? Zh : ((sector == 1) ? Fh : Oh);
  const int gbase = nt * 128 + wc * 64 + l15;
  const size_t wavebase = (((size_t)(mt * 9 + ntS) * 2 + wr) * 2 + wc) * 8192
                          + (size_t)lane * 8;
#pragma unroll
  for (int nr = 0; nr < 4; ++nr) {
    const float bv = bias[gbase + nr * 16];
#pragma unroll
    for (int mrh = 0; mrh < 4; ++mrh) {
      hx8 hv;
#pragma unroll
      for (int half = 0; half < 2; ++half) {
        f32x4 v = acc[mrh * 2 + half][nr];
#pragma unroll
        for (int rr = 0; rr < 4; ++rr) {
          float xv = v[rr] + bv;
          float s;
          if (sector == 0) {
            float e = __expf(2.0f * xv);   // tanh(x) = 1 - 2/(e^{2x}+1)
            s = 1.0f - 2.0f / (e + 1.0f);
          } else {
            s = 1.0f / (1.0f + __expf(-xv));
          }
          hv[half * 4 + rr] = (_Float16)s;
        }
      }
      __builtin_nontemporal_store(hv,
          (hx8*)(dst + wavebase + (size_t)(mrh * 4 + nr) * 512));
    }
  }
}

// ---- chunked parallel scan of h_t = (1-f)h + f z, CH=64 chunks of CL=32 ----
// chunk ch = tm*8 + wr*4 + mrh; within-chunk t5 = half*16 + kg*4 + r.
// grid 9216 = b(32) x hb(9) x chunk-pair(32); 256 thr = hloc(128) x sub(2).
__global__ __launch_bounds__(256) void scan1_k(const _Float16* __restrict__ Zh,
                                               const _Float16* __restrict__ Fh,
                                               f2* __restrict__ PQ) {
  const int bid = blockIdx.x;
  const int b = bid / 288;
  const int rem = bid - b * 288;
  const int hb = rem >> 5, cp = rem & 31;
  const int tid = threadIdx.x;
  const int hloc = tid & 127, sub = tid >> 7;
  const int ch = cp * 2 + sub;
  const int wc = hloc >> 6, nr = (hloc >> 4) & 3, l15 = hloc & 15;
  const int tm = ch >> 3, wr = (ch >> 2) & 1, mrh = ch & 3;
  const int mt = b * 8 + tm;

  const size_t base = unitOff(mt, hb, wr, wc, mrh, nr, 0, l15);
  hx8 vz[4], vf[4];
#pragma unroll
  for (int kg = 0; kg < 4; ++kg) {
    vz[kg] = __builtin_nontemporal_load((const hx8*)(Zh + base + kg * 128));
    vf[kg] = __builtin_nontemporal_load((const hx8*)(Fh + base + kg * 128));
  }
  float P = 1.f, Q = 0.f;
#pragma unroll
  for (int half = 0; half < 2; ++half) {
#pragma unroll
    for (int kg = 0; kg < 4; ++kg) {
#pragma unroll
      for (int s = 0; s < 4; ++s) {
        float fv = (float)vf[kg][half * 4 + s], a = 1.f - fv;
        P *= a;
        Q = a * Q + fv * (float)vz[kg][half * 4 + s];
      }
    }
  }
  f2 o; o[0] = P; o[1] = Q;
  PQ[((size_t)b * CH + ch) * HH + hb * 128 + hloc] = o;
}

// pass 2: sequential over 64 chunks per (b,h): start states
__global__ __launch_bounds__(256) void scan2_k(const f2* __restrict__ PQ,
                                               const float* __restrict__ h0,
                                               float* __restrict__ Hs) {
  const int idx = blockIdx.x * 256 + threadIdx.x;   // [b][h]
  const int b = idx / HH, h = idx - b * HH;
  float cur = h0[b * HH + h];
#pragma unroll 4
  for (int c = 0; c < CH; ++c) {
    Hs[((size_t)b * CH + c) * HH + h] = cur;
    f2 pq = PQ[((size_t)b * CH + c) * HH + h];
    cur = pq[0] * cur + pq[1];
  }
}

// pass 3: recompute within chunk (exact sequential fmaf), c = o*h.
// LDS transpose (64 t-rows x 128 h, stride 132); write phase lane-contiguous.
__global__ __launch_bounds__(256) void scan3_k(const _Float16* __restrict__ Zh,
                                               const _Float16* __restrict__ Fh,
                                               const _Float16* __restrict__ Oh,
                                               const float* __restrict__ Hs,
                                               float* __restrict__ Out) {
  __shared__ float buf[64 * 132];
  const int bid = blockIdx.x;
  const int b = bid / 288;
  const int rem = bid - b * 288;
  const int hb = rem >> 5, cp = rem & 31;
  const int tid = threadIdx.x;
  const int hloc = tid & 127, sub = tid >> 7;
  const int ch = cp * 2 + sub;
  const int h = hb * 128 + hloc;
  const int wc = hloc >> 6, nr = (hloc >> 4) & 3, l15 = hloc & 15;
  const int tm = ch >> 3, wr = (ch >> 2) & 1, mrh = ch & 3;
  const int mt = b * 8 + tm;

  const size_t base = unitOff(mt, hb, wr, wc, mrh, nr, 0, l15);
  hx8 vz[4], vf[4], vo[4];
#pragma unroll
  for (int kg = 0; kg < 4; ++kg) {
    vz[kg] = __builtin_nontemporal_load((const hx8*)(Zh + base + kg * 128));
    vf[kg] = __builtin_nontemporal_load((const hx8*)(Fh + base + kg * 128));
    vo[kg] = __builtin_nontemporal_load((const hx8*)(Oh + base + kg * 128));
  }
  float hcur = Hs[((size_t)b * CH + ch) * HH + h];
#pragma unroll
  for (int half = 0; half < 2; ++half) {
#pragma unroll
    for (int kg = 0; kg < 4; ++kg) {
#pragma unroll
      for (int s = 0; s < 4; ++s) {
        const int e = half * 4 + s;
        hcur = fmaf((float)vf[kg][e], (float)vz[kg][e] - hcur, hcur);
        buf[(sub * 32 + half * 16 + kg * 4 + s) * 132 + hloc] = (float)vo[kg][e] * hcur;
      }
    }
  }
  __syncthreads();
  // write phase: 32-lane group g (=tid>>5) owns rows g*8..g*8+7; lane32 covers
  // the row's 128 floats in 16-B chunks -> 512 B contiguous per instruction.
  const int lane32 = tid & 31, grp = tid >> 5;
  float* outb = Out + (size_t)(b * TT + cp * 64) * HH + hb * 128 + lane32 * 4;
#pragma unroll
  for (int rr = 0; rr < 8; ++rr) {
    const int row = grp * 8 + rr;
    f32x4 v = *(const f32x4*)&buf[row * 132 + lane32 * 4];
    __builtin_nontemporal_store(v, (f32x4*)(outb + (size_t)row * HH));
  }
}

extern "C" void kernel_launch(void* const* d_in, const int* in_sizes, int n_in,
                              void* d_out, int out_size, void* d_ws, size_t ws_size,
                              hipStream_t stream) {
  const float* x    = (const float*)d_in[0];
  const float* W    = (const float*)d_in[1];
  const float* bias = (const float*)d_in[2];
  const float* h0   = (const float*)d_in[3];
  float* Out = (float*)d_out;
  char* ws = (char*)d_ws;

  // ws layout
  const size_t A_BYTES  = (size_t)MT2 * KTL * 16384;       // 104,857,600
  const size_t W_BYTES  = (size_t)NT * KTL * 8192;         //   5,529,600
  const size_t G_BYTES  = (size_t)MM * HH * 2;             // 150,994,944 per gate (fp16)
  const size_t PQ_BYTES = (size_t)BB * CH * HH * 8;        //  18,874,368
  unsigned short* Aws = (unsigned short*)ws;
  unsigned short* Wws = (unsigned short*)(ws + A_BYTES);
  _Float16* Zh = (_Float16*)(ws + A_BYTES + W_BYTES);
  _Float16* Fh = (_Float16*)(ws + A_BYTES + W_BYTES + G_BYTES);
  _Float16* Oh = (_Float16*)(ws + A_BYTES + W_BYTES + 2 * G_BYTES);
  f2* PQ = (f2*)(ws + A_BYTES + W_BYTES + 3 * G_BYTES);
  float* Hs = (float*)(ws + A_BYTES + W_BYTES + 3 * G_BYTES + PQ_BYTES);
  (void)ws_size; (void)in_sizes; (void)n_in; (void)out_size;

  pack_W_k<<<dim3(NT, KTL), 256, 0, stream>>>(W, Wws);
  pack_A_k<<<dim3(MT2, KTL), 256, 0, stream>>>(x, Aws);
  gemm_k<<<MT2 * NT, 256, 0, stream>>>(Aws, Wws, bias, Zh, Fh, Oh);
  scan1_k<<<BB * 9 * 32, 256, 0, stream>>>(Zh, Fh, PQ);
  scan2_k<<<BB * HH / 256, 256, 0, stream>>>(PQ, h0, Hs);
  scan3_k<<<BB * 9 * 32, 256, 0, stream>>>(Zh, Fh, Oh, Hs, Out);
}